// Round 3
// baseline (447.261 us; speedup 1.0000x reference)
//
#include <hip/hip_runtime.h>

typedef unsigned short u16;
typedef u16 u16x4 __attribute__((ext_vector_type(4)));
typedef __bf16 bf16x8 __attribute__((ext_vector_type(8)));
typedef float f32x4 __attribute__((ext_vector_type(4)));

#define NROW 8192
#define CAP 128
#define D_IN 512
#define D_HID 256
#define D_OUT 128

__device__ __forceinline__ float leaky_f(float x) { return x > 0.f ? x : 0.25f * x; }

__device__ __forceinline__ u16 f2bf_rne(float f) {
  unsigned u = __float_as_uint(f);
  u += 0x7fffu + ((u >> 16) & 1u);
  return (u16)(u >> 16);
}
__device__ __forceinline__ float bf2f(u16 v) { return __uint_as_float(((unsigned)v) << 16); }
__device__ __forceinline__ void split_bf16(float f, u16& hi, u16& lo) {
  hi = f2bf_rne(f);
  float fh = __uint_as_float(((unsigned)hi) << 16);
  lo = f2bf_rne(f - fh);
}

// ---------------- weight pack: one thread per (n, k-octet); coalesced 16B stores ----------------
__global__ __launch_bounds__(256) void k_packw(
    const float* __restrict__ W1, u16* __restrict__ B1,
    const float* __restrict__ W2, u16* __restrict__ B2,
    const float* __restrict__ Wg, u16* __restrict__ B3) {
  const float* W; u16* Bt; int K, Nc, idx;
  int pb = blockIdx.x;                     // 112 blocks: 64 (W1) | 32 (W2) | 16 (Wg)
  if (pb < 64)      { W = W1; Bt = B1; K = D_IN;  Nc = D_HID; idx = pb * 256 + threadIdx.x; }
  else if (pb < 96) { W = W2; Bt = B2; K = D_HID; Nc = D_HID; idx = (pb - 64) * 256 + threadIdx.x; }
  else              { W = Wg; Bt = B3; K = D_HID; Nc = D_OUT; idx = (pb - 96) * 256 + threadIdx.x; }
  int ko8 = K >> 3;
  int n = idx / ko8, k0 = (idx % ko8) << 3;
  alignas(16) u16 hh[8], ll[8];
#pragma unroll
  for (int j = 0; j < 8; ++j) {
    float f = W[(size_t)(k0 + j) * Nc + n];
    split_bf16(f, hh[j], ll[j]);
  }
  size_t ro = (size_t)n * 2 * K;
  *(uint4*)(Bt + ro + k0)     = *(const uint4*)hh;
  *(uint4*)(Bt + ro + K + k0) = *(const uint4*)ll;
}

// ---------------- merged: blocks [0,512) = GEMM1 (x @ W1, bf16 out), blocks [512,8704) = CSR build ----------------
__global__ __launch_bounds__(256) void k_csr_gemm1(const float* __restrict__ adj,
    int* __restrict__ cnt, int* __restrict__ cols, float* __restrict__ vals,
    const float* __restrict__ X, const u16* __restrict__ Bt, u16* __restrict__ C) {
  __shared__ alignas(16) u16 Ah[64 * 40], Al[64 * 40];
  __shared__ alignas(16) u16 Bh[64 * 40], Bl[64 * 40];
  __shared__ int csrc;
  int b = blockIdx.x;
  int tid = threadIdx.x;
  if (b < 512) {  // GEMM1: 64x64 tile, in-register fp32->split-bf16 of x; K=512, N=256
    const int N = D_HID, K = D_IN;
    int bm = (b >> 2) * 64, bn = (b & 3) * 64;
    int wave = tid >> 6, lane = tid & 63, l15 = lane & 15, quad = lane >> 4;
    f32x4 acc[4] = {};
    int ar = tid >> 2, aj = (tid & 3) << 3;
    const float* Xrow = X + (size_t)(bm + ar) * K + aj;
    const u16* Brow = Bt + (size_t)(bn + ar) * (2 * K) + aj;
    for (int k0 = 0; k0 < K; k0 += 32) {
      alignas(16) u16 hh[8], ll[8];
      float xv[8];
      *(float4*)(xv)     = *(const float4*)(Xrow + k0);
      *(float4*)(xv + 4) = *(const float4*)(Xrow + k0 + 4);
#pragma unroll
      for (int e = 0; e < 8; ++e) split_bf16(xv[e], hh[e], ll[e]);
      *(uint4*)(&Ah[ar * 40 + aj]) = *(const uint4*)hh;
      *(uint4*)(&Al[ar * 40 + aj]) = *(const uint4*)ll;
      *(uint4*)(&Bh[ar * 40 + aj]) = *(const uint4*)(Brow + k0);
      *(uint4*)(&Bl[ar * 40 + aj]) = *(const uint4*)(Brow + K + k0);
      __syncthreads();
      bf16x8 afh = *(const bf16x8*)(&Ah[(wave * 16 + l15) * 40 + quad * 8]);
      bf16x8 afl = *(const bf16x8*)(&Al[(wave * 16 + l15) * 40 + quad * 8]);
#pragma unroll
      for (int c = 0; c < 4; ++c) {
        bf16x8 bfh = *(const bf16x8*)(&Bh[(c * 16 + l15) * 40 + quad * 8]);
        bf16x8 bfl = *(const bf16x8*)(&Bl[(c * 16 + l15) * 40 + quad * 8]);
        acc[c] = __builtin_amdgcn_mfma_f32_16x16x32_bf16(afh, bfh, acc[c], 0, 0, 0);
        acc[c] = __builtin_amdgcn_mfma_f32_16x16x32_bf16(afh, bfl, acc[c], 0, 0, 0);
        acc[c] = __builtin_amdgcn_mfma_f32_16x16x32_bf16(afl, bfh, acc[c], 0, 0, 0);
      }
      __syncthreads();
    }
#pragma unroll
    for (int c = 0; c < 4; ++c)
#pragma unroll
      for (int rg = 0; rg < 4; ++rg) {
        int rowi = bm + wave * 16 + quad * 4 + rg;   // C/D: col=lane&15, row=quad*4+reg
        int coli = bn + c * 16 + l15;
        C[(size_t)rowi * N + coli] = f2bf_rne(acc[c][rg]);
      }
    return;
  }
  // CSR row build — ballot/prefix-scan, one LDS atomic per wave-iteration (order irrelevant)
  int i = b - 512;
  if (tid == 0) csrc = 0;
  __syncthreads();
  int lane = tid & 63;
  const float4* row = (const float4*)(adj + (size_t)i * NROW);
  for (int j4 = tid; j4 < NROW / 4; j4 += 256) {
    float4 v = row[j4];
    int base = j4 * 4;
    bool p0 = v.x > 0.f, p1 = v.y > 0.f, p2 = v.z > 0.f, p3 = v.w > 0.f;
    unsigned long long m0 = __ballot(p0), m1 = __ballot(p1);
    unsigned long long m2 = __ballot(p2), m3 = __ballot(p3);
    int c0 = __popcll(m0), c1 = __popcll(m1), c2 = __popcll(m2), c3 = __popcll(m3);
    int tot = c0 + c1 + c2 + c3;
    if (tot) {
      int wbase = 0;
      if (lane == 0) wbase = atomicAdd(&csrc, tot);
      wbase = __shfl(wbase, 0);
      unsigned long long lm = (1ULL << lane) - 1ULL;
      int o0 = wbase + __popcll(m0 & lm);
      int o1 = wbase + c0 + __popcll(m1 & lm);
      int o2 = wbase + c0 + c1 + __popcll(m2 & lm);
      int o3 = wbase + c0 + c1 + c2 + __popcll(m3 & lm);
      if (p0 && o0 < CAP) { cols[i*CAP+o0] = base;   vals[i*CAP+o0] = v.x; }
      if (p1 && o1 < CAP) { cols[i*CAP+o1] = base+1; vals[i*CAP+o1] = v.y; }
      if (p2 && o2 < CAP) { cols[i*CAP+o2] = base+2; vals[i*CAP+o2] = v.z; }
      if (p3 && o3 < CAP) { cols[i*CAP+o3] = base+3; vals[i*CAP+o3] = v.w; }
    }
  }
  __syncthreads();
  if (tid == 0) cnt[i] = (csrc < CAP) ? csrc : CAP;
}

// ======== fused SpMM (row-gather, fp32 acc) + split-bf16 into LDS + MFMA GEMM ========
// Block = 16 rows. Phase 1: 4 rows/wave, 8-deep gather ILP; split hi/lo written to
// K-chunked LDS A (proven stride-40 fragment layout). One barrier. Phase 2: 3-pass
// split-bf16 MFMA; B fragments read DIRECT from global (B pack is L2-hot) -> no B
// staging, no per-k0 barriers, compiler pipelines loads across the unrolled K loop.

// gather one row's 256 bf16 features weighted by CSR vals; lane owns feats [4L,4L+4)
__device__ __forceinline__ float4 gather_row256(const u16* __restrict__ Hin,
    const int* scw, const float* svw, int n, int lane) {
  float4 acc = {0.f, 0.f, 0.f, 0.f};
  int k = 0;
  for (; k + 7 < n; k += 8) {
    int   c0 = scw[k],     c1 = scw[k + 1], c2 = scw[k + 2], c3 = scw[k + 3];
    int   c4 = scw[k + 4], c5 = scw[k + 5], c6 = scw[k + 6], c7 = scw[k + 7];
    float w0 = svw[k],     w1 = svw[k + 1], w2 = svw[k + 2], w3 = svw[k + 3];
    float w4 = svw[k + 4], w5 = svw[k + 5], w6 = svw[k + 6], w7 = svw[k + 7];
    u16x4 v0 = *(const u16x4*)(Hin + (size_t)c0 * 256 + 4 * lane);
    u16x4 v1 = *(const u16x4*)(Hin + (size_t)c1 * 256 + 4 * lane);
    u16x4 v2 = *(const u16x4*)(Hin + (size_t)c2 * 256 + 4 * lane);
    u16x4 v3 = *(const u16x4*)(Hin + (size_t)c3 * 256 + 4 * lane);
    u16x4 v4 = *(const u16x4*)(Hin + (size_t)c4 * 256 + 4 * lane);
    u16x4 v5 = *(const u16x4*)(Hin + (size_t)c5 * 256 + 4 * lane);
    u16x4 v6 = *(const u16x4*)(Hin + (size_t)c6 * 256 + 4 * lane);
    u16x4 v7 = *(const u16x4*)(Hin + (size_t)c7 * 256 + 4 * lane);
    acc.x = fmaf(w0, bf2f(v0[0]), acc.x); acc.y = fmaf(w0, bf2f(v0[1]), acc.y);
    acc.z = fmaf(w0, bf2f(v0[2]), acc.z); acc.w = fmaf(w0, bf2f(v0[3]), acc.w);
    acc.x = fmaf(w1, bf2f(v1[0]), acc.x); acc.y = fmaf(w1, bf2f(v1[1]), acc.y);
    acc.z = fmaf(w1, bf2f(v1[2]), acc.z); acc.w = fmaf(w1, bf2f(v1[3]), acc.w);
    acc.x = fmaf(w2, bf2f(v2[0]), acc.x); acc.y = fmaf(w2, bf2f(v2[1]), acc.y);
    acc.z = fmaf(w2, bf2f(v2[2]), acc.z); acc.w = fmaf(w2, bf2f(v2[3]), acc.w);
    acc.x = fmaf(w3, bf2f(v3[0]), acc.x); acc.y = fmaf(w3, bf2f(v3[1]), acc.y);
    acc.z = fmaf(w3, bf2f(v3[2]), acc.z); acc.w = fmaf(w3, bf2f(v3[3]), acc.w);
    acc.x = fmaf(w4, bf2f(v4[0]), acc.x); acc.y = fmaf(w4, bf2f(v4[1]), acc.y);
    acc.z = fmaf(w4, bf2f(v4[2]), acc.z); acc.w = fmaf(w4, bf2f(v4[3]), acc.w);
    acc.x = fmaf(w5, bf2f(v5[0]), acc.x); acc.y = fmaf(w5, bf2f(v5[1]), acc.y);
    acc.z = fmaf(w5, bf2f(v5[2]), acc.z); acc.w = fmaf(w5, bf2f(v5[3]), acc.w);
    acc.x = fmaf(w6, bf2f(v6[0]), acc.x); acc.y = fmaf(w6, bf2f(v6[1]), acc.y);
    acc.z = fmaf(w6, bf2f(v6[2]), acc.z); acc.w = fmaf(w6, bf2f(v6[3]), acc.w);
    acc.x = fmaf(w7, bf2f(v7[0]), acc.x); acc.y = fmaf(w7, bf2f(v7[1]), acc.y);
    acc.z = fmaf(w7, bf2f(v7[2]), acc.z); acc.w = fmaf(w7, bf2f(v7[3]), acc.w);
  }
  for (; k < n; ++k) {
    float wv = svw[k];
    u16x4 v = *(const u16x4*)(Hin + (size_t)scw[k] * 256 + 4 * lane);
    acc.x = fmaf(wv, bf2f(v[0]), acc.x); acc.y = fmaf(wv, bf2f(v[1]), acc.y);
    acc.z = fmaf(wv, bf2f(v[2]), acc.z); acc.w = fmaf(wv, bf2f(v[3]), acc.w);
  }
  return acc;
}

// ---------------- fuse1: x1 = leaky(adj@H0 + b1); T2 = x1 @ W2 (bf16 out, N=256) ----------------
__global__ __launch_bounds__(256) void k_fuse1(const u16* __restrict__ Hin,
    const float* __restrict__ bias, const int* __restrict__ cnt,
    const int* __restrict__ cols, const float* __restrict__ vals,
    const u16* __restrict__ Bt, u16* __restrict__ Cout) {
  __shared__ alignas(16) u16 AhF[8 * 16 * 40], AlF[8 * 16 * 40];  // K-chunked split A (16 rows)
  __shared__ int   sc[4 * CAP];
  __shared__ float sv[4 * CAP];
  int tid = threadIdx.x;
  int wave = tid >> 6, lane = tid & 63, l15 = lane & 15, quad = lane >> 4;
  int bm = blockIdx.x * 16;
  // -------- phase 1: spmm rows (4 per wave) --------
  int* scw = sc + wave * CAP;
  float* svw = sv + wave * CAP;
  float4 bv = ((const float4*)bias)[lane];
#pragma unroll
  for (int rr = 0; rr < 4; ++rr) {
    int r = wave * 4 + rr;
    int i = bm + r;
    int n = cnt[i];
    if (lane < n)      { scw[lane]      = cols[i*CAP+lane];      svw[lane]      = vals[i*CAP+lane]; }
    if (lane + 64 < n) { scw[lane + 64] = cols[i*CAP+lane+64];   svw[lane + 64] = vals[i*CAP+lane+64]; }
    float4 acc = gather_row256(Hin, scw, svw, n, lane);
    float r4[4] = { leaky_f(acc.x + bv.x), leaky_f(acc.y + bv.y),
                    leaky_f(acc.z + bv.z), leaky_f(acc.w + bv.w) };
    u16x4 hi4, lo4;
#pragma unroll
    for (int e = 0; e < 4; ++e) { u16 hh, ll; split_bf16(r4[e], hh, ll); hi4[e] = hh; lo4[e] = ll; }
    int dst = (lane >> 3) * 640 + r * 40 + (lane & 7) * 4;
    *(u16x4*)(&AhF[dst]) = hi4;
    *(u16x4*)(&AlF[dst]) = lo4;
  }
  __syncthreads();
  // -------- phase 2: 16x256 GEMM, B direct from global (L2-hot), no barriers --------
#pragma unroll
  for (int hN = 0; hN < 2; ++hN) {
    f32x4 acc[2] = {};
#pragma unroll
    for (int k0 = 0; k0 < D_HID; k0 += 32) {
      bf16x8 afh = *(const bf16x8*)(&AhF[(k0 >> 5) * 640 + l15 * 40 + quad * 8]);
      bf16x8 afl = *(const bf16x8*)(&AlF[(k0 >> 5) * 640 + l15 * 40 + quad * 8]);
#pragma unroll
      for (int c = 0; c < 2; ++c) {
        int col = hN * 128 + wave * 32 + c * 16 + l15;
        const u16* bp = Bt + (size_t)col * (2 * D_HID) + k0 + quad * 8;
        bf16x8 bfh = *(const bf16x8*)(bp);
        bf16x8 bfl = *(const bf16x8*)(bp + D_HID);
        acc[c] = __builtin_amdgcn_mfma_f32_16x16x32_bf16(afh, bfh, acc[c], 0, 0, 0);
        acc[c] = __builtin_amdgcn_mfma_f32_16x16x32_bf16(afh, bfl, acc[c], 0, 0, 0);
        acc[c] = __builtin_amdgcn_mfma_f32_16x16x32_bf16(afl, bfh, acc[c], 0, 0, 0);
      }
    }
#pragma unroll
    for (int c = 0; c < 2; ++c)
#pragma unroll
      for (int rg = 0; rg < 4; ++rg) {
        int rowi = bm + quad * 4 + rg;
        int coli = hN * 128 + wave * 32 + c * 16 + l15;
        Cout[(size_t)rowi * 256 + coli] = f2bf_rne(acc[c][rg]);
      }
  }
}

// ---------------- fuse2: x2 = leaky(adj@T2 + b2); h = x2 @ Wg (bf16) + fused s1/s2 ----------------
__global__ __launch_bounds__(256) void k_fuse2(const u16* __restrict__ Hin,
    const float* __restrict__ bias, const int* __restrict__ cnt,
    const int* __restrict__ cols, const float* __restrict__ vals,
    const u16* __restrict__ Bt, u16* __restrict__ Hb,
    const float* __restrict__ aptr, float* __restrict__ s1, float* __restrict__ s2) {
  __shared__ alignas(16) u16 AhF[8 * 16 * 40], AlF[8 * 16 * 40];
  __shared__ int   sc[4 * CAP];
  __shared__ float sv[4 * CAP];
  __shared__ float sp1[4][16], sp2[4][16];
  int tid = threadIdx.x;
  int wave = tid >> 6, lane = tid & 63, l15 = lane & 15, quad = lane >> 4;
  int bm = blockIdx.x * 16;
  // -------- phase 1: spmm rows (4 per wave) --------
  int* scw = sc + wave * CAP;
  float* svw = sv + wave * CAP;
  float4 bv = ((const float4*)bias)[lane];
#pragma unroll
  for (int rr = 0; rr < 4; ++rr) {
    int r = wave * 4 + rr;
    int i = bm + r;
    int n = cnt[i];
    if (lane < n)      { scw[lane]      = cols[i*CAP+lane];      svw[lane]      = vals[i*CAP+lane]; }
    if (lane + 64 < n) { scw[lane + 64] = cols[i*CAP+lane+64];   svw[lane + 64] = vals[i*CAP+lane+64]; }
    float4 acc = gather_row256(Hin, scw, svw, n, lane);
    float r4[4] = { leaky_f(acc.x + bv.x), leaky_f(acc.y + bv.y),
                    leaky_f(acc.z + bv.z), leaky_f(acc.w + bv.w) };
    u16x4 hi4, lo4;
#pragma unroll
    for (int e = 0; e < 4; ++e) { u16 hh, ll; split_bf16(r4[e], hh, ll); hi4[e] = hh; lo4[e] = ll; }
    int dst = (lane >> 3) * 640 + r * 40 + (lane & 7) * 4;
    *(u16x4*)(&AhF[dst]) = hi4;
    *(u16x4*)(&AlF[dst]) = lo4;
  }
  __syncthreads();
  // -------- phase 2: 16x128 GEMM, B direct from global; fp32 accs feed s1/s2 --------
  f32x4 acc[2] = {};
#pragma unroll
  for (int k0 = 0; k0 < D_HID; k0 += 32) {
    bf16x8 afh = *(const bf16x8*)(&AhF[(k0 >> 5) * 640 + l15 * 40 + quad * 8]);
    bf16x8 afl = *(const bf16x8*)(&AlF[(k0 >> 5) * 640 + l15 * 40 + quad * 8]);
#pragma unroll
    for (int c = 0; c < 2; ++c) {
      int col = wave * 32 + c * 16 + l15;
      const u16* bp = Bt + (size_t)col * (2 * D_HID) + k0 + quad * 8;
      bf16x8 bfh = *(const bf16x8*)(bp);
      bf16x8 bfl = *(const bf16x8*)(bp + D_HID);
      acc[c] = __builtin_amdgcn_mfma_f32_16x16x32_bf16(afh, bfh, acc[c], 0, 0, 0);
      acc[c] = __builtin_amdgcn_mfma_f32_16x16x32_bf16(afh, bfl, acc[c], 0, 0, 0);
      acc[c] = __builtin_amdgcn_mfma_f32_16x16x32_bf16(afl, bfh, acc[c], 0, 0, 0);
    }
  }
  // h write (bf16)
#pragma unroll
  for (int c = 0; c < 2; ++c)
#pragma unroll
    for (int rg = 0; rg < 4; ++rg) {
      int rowi = bm + quad * 4 + rg;
      int coli = wave * 32 + c * 16 + l15;
      Hb[(size_t)rowi * 128 + coli] = f2bf_rne(acc[c][rg]);
    }
  // fused s1/s2 from fp32 accumulators (exact logit path)
  float a1v[2], a2v[2];
#pragma unroll
  for (int c = 0; c < 2; ++c) {
    a1v[c] = aptr[wave * 32 + c * 16 + l15];
    a2v[c] = aptr[128 + wave * 32 + c * 16 + l15];
  }
#pragma unroll
  for (int rg = 0; rg < 4; ++rg) {
    float p1 = 0.f, p2 = 0.f;
#pragma unroll
    for (int c = 0; c < 2; ++c) { p1 = fmaf(acc[c][rg], a1v[c], p1); p2 = fmaf(acc[c][rg], a2v[c], p2); }
#pragma unroll
    for (int m = 1; m < 16; m <<= 1) { p1 += __shfl_xor(p1, m); p2 += __shfl_xor(p2, m); }
    if (l15 == 0) {
      int rloc = quad * 4 + rg;
      sp1[wave][rloc] = p1; sp2[wave][rloc] = p2;
    }
  }
  __syncthreads();
  if (tid < 16) {
    s1[bm + tid] = sp1[0][tid] + sp1[1][tid] + sp1[2][tid] + sp1[3][tid];
    s2[bm + tid] = sp2[0][tid] + sp2[1][tid] + sp2[2][tid] + sp2[3][tid];
  }
}

// ---------------- attention: ONE WAVE PER ROW; shuffle softmax; 2-half x 4-deep gather MLP ----------------
__global__ __launch_bounds__(256) void k_attn(const u16* __restrict__ Hb,
    const float* __restrict__ s1, const float* __restrict__ s2,
    const int* __restrict__ cnt, const int* __restrict__ cols, float* __restrict__ out) {
  __shared__ int sc[4][CAP];
  __shared__ float sp[4][CAP];
  int w = threadIdx.x >> 6, lane = threadIdx.x & 63;
  int i = blockIdx.x * 4 + w;
  int n = cnt[i];
  float s1i = s1[i];
  float e0 = -1e30f, e1 = -1e30f;
  if (lane < n)      { int c = cols[i * CAP + lane];      sc[w][lane]      = c; e0 = leaky_f(s1i + s2[c]); }
  if (lane + 64 < n) { int c = cols[i * CAP + lane + 64]; sc[w][lane + 64] = c; e1 = leaky_f(s1i + s2[c]); }
  float m = fmaxf(e0, e1);
#pragma unroll
  for (int o = 32; o > 0; o >>= 1) m = fmaxf(m, __shfl_xor(m, o));
  float p0 = (lane < n)      ? expf(e0 - m) : 0.f;
  float p1 = (lane + 64 < n) ? expf(e1 - m) : 0.f;
  if (lane < n)      sp[w][lane]      = p0;
  if (lane + 64 < n) sp[w][lane + 64] = p1;
  float s = p0 + p1;
#pragma unroll
  for (int o = 32; o > 0; o >>= 1) s += __shfl_xor(s, o);
  float inv = (n > 0) ? 1.0f / s : 0.f;
  __syncthreads();
  int half = lane >> 5, t32 = lane & 31;
  float4 acc = {0.f, 0.f, 0.f, 0.f};
  int k = half;
  for (; k + 6 < n; k += 8) {   // per half-wave: 4 independent row-gathers in flight
    int   c0 = sc[w][k],     c1 = sc[w][k + 2], c2 = sc[w][k + 4], c3 = sc[w][k + 6];
    float w0 = sp[w][k],     w1 = sp[w][k + 2], w2 = sp[w][k + 4], w3 = sp[w][k + 6];
    u16x4 a0 = *(const u16x4*)(Hb + (size_t)c0 * 128 + 4 * t32);
    u16x4 a1 = *(const u16x4*)(Hb + (size_t)c1 * 128 + 4 * t32);
    u16x4 a2 = *(const u16x4*)(Hb + (size_t)c2 * 128 + 4 * t32);
    u16x4 a3 = *(const u16x4*)(Hb + (size_t)c3 * 128 + 4 * t32);
    acc.x = fmaf(w0, bf2f(a0[0]), acc.x); acc.y = fmaf(w0, bf2f(a0[1]), acc.y);
    acc.z = fmaf(w0, bf2f(a0[2]), acc.z); acc.w = fmaf(w0, bf2f(a0[3]), acc.w);
    acc.x = fmaf(w1, bf2f(a1[0]), acc.x); acc.y = fmaf(w1, bf2f(a1[1]), acc.y);
    acc.z = fmaf(w1, bf2f(a1[2]), acc.z); acc.w = fmaf(w1, bf2f(a1[3]), acc.w);
    acc.x = fmaf(w2, bf2f(a2[0]), acc.x); acc.y = fmaf(w2, bf2f(a2[1]), acc.y);
    acc.z = fmaf(w2, bf2f(a2[2]), acc.z); acc.w = fmaf(w2, bf2f(a2[3]), acc.w);
    acc.x = fmaf(w3, bf2f(a3[0]), acc.x); acc.y = fmaf(w3, bf2f(a3[1]), acc.y);
    acc.z = fmaf(w3, bf2f(a3[2]), acc.z); acc.w = fmaf(w3, bf2f(a3[3]), acc.w);
  }
  for (; k < n; k += 2) {
    float wv = sp[w][k];
    u16x4 a = *(const u16x4*)(Hb + (size_t)sc[w][k] * 128 + 4 * t32);
    acc.x = fmaf(wv, bf2f(a[0]), acc.x); acc.y = fmaf(wv, bf2f(a[1]), acc.y);
    acc.z = fmaf(wv, bf2f(a[2]), acc.z); acc.w = fmaf(wv, bf2f(a[3]), acc.w);
  }
  acc.x += __shfl_xor(acc.x, 32);
  acc.y += __shfl_xor(acc.y, 32);
  acc.z += __shfl_xor(acc.z, 32);
  acc.w += __shfl_xor(acc.w, 32);
  if (lane < 32) {
    float4 r;
    r.x = leaky_f(acc.x * inv);
    r.y = leaky_f(acc.y * inv);
    r.z = leaky_f(acc.z * inv);
    r.w = leaky_f(acc.w * inv);
    float4* o4 = (float4*)out;
    if (lane < 16) o4[(size_t)i * 16 + lane] = r;                               // mu
    else           o4[(size_t)NROW * 16 + (size_t)i * 16 + (lane - 16)] = r;    // logvar
  }
}

extern "C" void kernel_launch(void* const* d_in, const int* in_sizes, int n_in,
                              void* d_out, int out_size, void* d_ws, size_t ws_size,
                              hipStream_t stream) {
  const float* x   = (const float*)d_in[0];
  const float* adj = (const float*)d_in[1];
  const float* W1  = (const float*)d_in[2];
  const float* b1  = (const float*)d_in[3];
  const float* W2  = (const float*)d_in[4];
  const float* b2  = (const float*)d_in[5];
  const float* Wg  = (const float*)d_in[6];
  const float* a   = (const float*)d_in[7];
  float* out = (float*)d_out;

  char* ws = (char*)d_ws;
  int*   row_cnt  = (int*)  (ws + 0);          //  32 KB
  int*   row_cols = (int*)  (ws + 32768);      //   4 MB
  float* row_vals = (float*)(ws + 4227072);    //   4 MB
  u16*   B1t      = (u16*)  (ws + 8421376);    // 512 KB (256 x 1024)
  u16*   B2t      = (u16*)  (ws + 8945664);    // 256 KB (256 x 512)
  u16*   B3t      = (u16*)  (ws + 9207808);    // 128 KB (128 x 512)
  float* s1       = (float*)(ws + 9338880);    //  32 KB
  float* s2       = (float*)(ws + 9371648);    //  32 KB
  u16*   hbf      = (u16*)  (ws + 9404416);    //   2 MB (8192 x 128 bf16)
  u16*   H0T2     = (u16*)  (ws + 13598720);   //   4 MB (8192 x 256 bf16)
  u16*   T2       = (u16*)  (ws + 21987328);   //   4 MB (8192 x 256 bf16)

  // 1. weight pack (coalesced-store mapping; must precede gemm1)
  k_packw<<<112, 256, 0, stream>>>(W1, B1t, W2, B2t, Wg, B3t);
  // 2. merged: GEMM1 (512 compute blocks, bf16 out) + ballot-scan CSR build (8192 HBM blocks)
  k_csr_gemm1<<<512 + NROW, 256, 0, stream>>>(adj, row_cnt, row_cols, row_vals, x, B1t, H0T2);
  // 3. fused: x1 = leaky(adj@H0 + b1); T2 = x1 @ W2
  k_fuse1<<<NROW / 16, 256, 0, stream>>>(H0T2, b1, row_cnt, row_cols, row_vals, B2t, T2);
  // 4. fused: x2 = leaky(adj@T2 + b2); h = x2 @ Wg + fused fp32 s1/s2
  k_fuse2<<<NROW / 16, 256, 0, stream>>>(T2, b2, row_cnt, row_cols, row_vals, B3t, hbf, a, s1, s2);
  // 5. masked softmax attention (wave-per-row, shuffle softmax) + bf16 aggregate + output split
  k_attn<<<NROW / 4, 256, 0, stream>>>(hbf, s1, s2, row_cnt, row_cols, out);
}

// Round 4
// 437.701 us; speedup vs baseline: 1.0218x; 1.0218x over previous
//
#include <hip/hip_runtime.h>

typedef unsigned short u16;
typedef u16 u16x4 __attribute__((ext_vector_type(4)));
typedef __bf16 bf16x8 __attribute__((ext_vector_type(8)));
typedef float f32x4 __attribute__((ext_vector_type(4)));

#define NROW 8192
#define CAP 128
#define D_IN 512
#define D_HID 256
#define D_OUT 128

__device__ __forceinline__ float leaky_f(float x) { return x > 0.f ? x : 0.25f * x; }

__device__ __forceinline__ u16 f2bf_rne(float f) {
  unsigned u = __float_as_uint(f);
  u += 0x7fffu + ((u >> 16) & 1u);
  return (u16)(u >> 16);
}
__device__ __forceinline__ float bf2f(u16 v) { return __uint_as_float(((unsigned)v) << 16); }
__device__ __forceinline__ void split_bf16(float f, u16& hi, u16& lo) {
  hi = f2bf_rne(f);
  float fh = __uint_as_float(((unsigned)hi) << 16);
  lo = f2bf_rne(f - fh);
}

// ---------------- weight pack: one thread per (n, k-octet); coalesced 16B stores ----------------
__global__ __launch_bounds__(256) void k_packw(
    const float* __restrict__ W1, u16* __restrict__ B1,
    const float* __restrict__ W2, u16* __restrict__ B2,
    const float* __restrict__ Wg, u16* __restrict__ B3) {
  const float* W; u16* Bt; int K, Nc, idx;
  int pb = blockIdx.x;                     // 112 blocks: 64 (W1) | 32 (W2) | 16 (Wg)
  if (pb < 64)      { W = W1; Bt = B1; K = D_IN;  Nc = D_HID; idx = pb * 256 + threadIdx.x; }
  else if (pb < 96) { W = W2; Bt = B2; K = D_HID; Nc = D_HID; idx = (pb - 64) * 256 + threadIdx.x; }
  else              { W = Wg; Bt = B3; K = D_HID; Nc = D_OUT; idx = (pb - 96) * 256 + threadIdx.x; }
  int ko8 = K >> 3;
  int n = idx / ko8, k0 = (idx % ko8) << 3;
  alignas(16) u16 hh[8], ll[8];
#pragma unroll
  for (int j = 0; j < 8; ++j) {
    float f = W[(size_t)(k0 + j) * Nc + n];
    split_bf16(f, hh[j], ll[j]);
  }
  size_t ro = (size_t)n * 2 * K;
  *(uint4*)(Bt + ro + k0)     = *(const uint4*)hh;
  *(uint4*)(Bt + ro + K + k0) = *(const uint4*)ll;
}

// ---------------- merged: blocks [0,512) = GEMM1 (x @ W1, bf16 out), blocks [512,8704) = CSR build ----------------
__global__ __launch_bounds__(256) void k_csr_gemm1(const float* __restrict__ adj,
    int* __restrict__ cnt, int* __restrict__ cols, float* __restrict__ vals,
    const float* __restrict__ X, const u16* __restrict__ Bt, u16* __restrict__ C) {
  __shared__ alignas(16) u16 Ah[64 * 40], Al[64 * 40];
  __shared__ alignas(16) u16 Bh[64 * 40], Bl[64 * 40];
  __shared__ int csrc;
  int b = blockIdx.x;
  int tid = threadIdx.x;
  if (b < 512) {  // GEMM1: 64x64 tile, in-register fp32->split-bf16 of x; K=512, N=256
    const int N = D_HID, K = D_IN;
    int bm = (b >> 2) * 64, bn = (b & 3) * 64;
    int wave = tid >> 6, lane = tid & 63, l15 = lane & 15, quad = lane >> 4;
    f32x4 acc[4] = {};
    int ar = tid >> 2, aj = (tid & 3) << 3;
    const float* Xrow = X + (size_t)(bm + ar) * K + aj;
    const u16* Brow = Bt + (size_t)(bn + ar) * (2 * K) + aj;
    for (int k0 = 0; k0 < K; k0 += 32) {
      alignas(16) u16 hh[8], ll[8];
      float xv[8];
      *(float4*)(xv)     = *(const float4*)(Xrow + k0);
      *(float4*)(xv + 4) = *(const float4*)(Xrow + k0 + 4);
#pragma unroll
      for (int e = 0; e < 8; ++e) split_bf16(xv[e], hh[e], ll[e]);
      *(uint4*)(&Ah[ar * 40 + aj]) = *(const uint4*)hh;
      *(uint4*)(&Al[ar * 40 + aj]) = *(const uint4*)ll;
      *(uint4*)(&Bh[ar * 40 + aj]) = *(const uint4*)(Brow + k0);
      *(uint4*)(&Bl[ar * 40 + aj]) = *(const uint4*)(Brow + K + k0);
      __syncthreads();
      bf16x8 afh = *(const bf16x8*)(&Ah[(wave * 16 + l15) * 40 + quad * 8]);
      bf16x8 afl = *(const bf16x8*)(&Al[(wave * 16 + l15) * 40 + quad * 8]);
#pragma unroll
      for (int c = 0; c < 4; ++c) {
        bf16x8 bfh = *(const bf16x8*)(&Bh[(c * 16 + l15) * 40 + quad * 8]);
        bf16x8 bfl = *(const bf16x8*)(&Bl[(c * 16 + l15) * 40 + quad * 8]);
        acc[c] = __builtin_amdgcn_mfma_f32_16x16x32_bf16(afh, bfh, acc[c], 0, 0, 0);
        acc[c] = __builtin_amdgcn_mfma_f32_16x16x32_bf16(afh, bfl, acc[c], 0, 0, 0);
        acc[c] = __builtin_amdgcn_mfma_f32_16x16x32_bf16(afl, bfh, acc[c], 0, 0, 0);
      }
      __syncthreads();
    }
#pragma unroll
    for (int c = 0; c < 4; ++c)
#pragma unroll
      for (int rg = 0; rg < 4; ++rg) {
        int rowi = bm + wave * 16 + quad * 4 + rg;   // C/D: col=lane&15, row=quad*4+reg
        int coli = bn + c * 16 + l15;
        C[(size_t)rowi * N + coli] = f2bf_rne(acc[c][rg]);
      }
    return;
  }
  // CSR row build — ballot/prefix-scan, one LDS atomic per wave-iteration (order irrelevant)
  int i = b - 512;
  if (tid == 0) csrc = 0;
  __syncthreads();
  int lane = tid & 63;
  const float4* row = (const float4*)(adj + (size_t)i * NROW);
  for (int j4 = tid; j4 < NROW / 4; j4 += 256) {
    float4 v = row[j4];
    int base = j4 * 4;
    bool p0 = v.x > 0.f, p1 = v.y > 0.f, p2 = v.z > 0.f, p3 = v.w > 0.f;
    unsigned long long m0 = __ballot(p0), m1 = __ballot(p1);
    unsigned long long m2 = __ballot(p2), m3 = __ballot(p3);
    int c0 = __popcll(m0), c1 = __popcll(m1), c2 = __popcll(m2), c3 = __popcll(m3);
    int tot = c0 + c1 + c2 + c3;
    if (tot) {
      int wbase = 0;
      if (lane == 0) wbase = atomicAdd(&csrc, tot);
      wbase = __shfl(wbase, 0);
      unsigned long long lm = (1ULL << lane) - 1ULL;
      int o0 = wbase + __popcll(m0 & lm);
      int o1 = wbase + c0 + __popcll(m1 & lm);
      int o2 = wbase + c0 + c1 + __popcll(m2 & lm);
      int o3 = wbase + c0 + c1 + c2 + __popcll(m3 & lm);
      if (p0 && o0 < CAP) { cols[i*CAP+o0] = base;   vals[i*CAP+o0] = v.x; }
      if (p1 && o1 < CAP) { cols[i*CAP+o1] = base+1; vals[i*CAP+o1] = v.y; }
      if (p2 && o2 < CAP) { cols[i*CAP+o2] = base+2; vals[i*CAP+o2] = v.z; }
      if (p3 && o3 < CAP) { cols[i*CAP+o3] = base+3; vals[i*CAP+o3] = v.w; }
    }
  }
  __syncthreads();
  if (tid == 0) cnt[i] = (csrc < CAP) ? csrc : CAP;
}

// ======== fused SpMM (row-gather, fp32 acc) + split-bf16 into LDS + MFMA GEMM ========
// Block = 16 rows, 8 waves (512 thr). Phase 1: 2 rows/wave, both rows' CSR lists
// preloaded to per-(wave,row) LDS slots, then 8-deep gather ILP per row. One barrier.
// Phase 2: 3-pass split-bf16 MFMA; B fragments read DIRECT from global (L2-hot).

// gather one row's 256 bf16 features weighted by CSR vals; lane owns feats [4L,4L+4)
__device__ __forceinline__ float4 gather_row256(const u16* __restrict__ Hin,
    const int* scw, const float* svw, int n, int lane) {
  float4 acc = {0.f, 0.f, 0.f, 0.f};
  int k = 0;
  for (; k + 7 < n; k += 8) {
    int   c0 = scw[k],     c1 = scw[k + 1], c2 = scw[k + 2], c3 = scw[k + 3];
    int   c4 = scw[k + 4], c5 = scw[k + 5], c6 = scw[k + 6], c7 = scw[k + 7];
    float w0 = svw[k],     w1 = svw[k + 1], w2 = svw[k + 2], w3 = svw[k + 3];
    float w4 = svw[k + 4], w5 = svw[k + 5], w6 = svw[k + 6], w7 = svw[k + 7];
    u16x4 v0 = *(const u16x4*)(Hin + (size_t)c0 * 256 + 4 * lane);
    u16x4 v1 = *(const u16x4*)(Hin + (size_t)c1 * 256 + 4 * lane);
    u16x4 v2 = *(const u16x4*)(Hin + (size_t)c2 * 256 + 4 * lane);
    u16x4 v3 = *(const u16x4*)(Hin + (size_t)c3 * 256 + 4 * lane);
    u16x4 v4 = *(const u16x4*)(Hin + (size_t)c4 * 256 + 4 * lane);
    u16x4 v5 = *(const u16x4*)(Hin + (size_t)c5 * 256 + 4 * lane);
    u16x4 v6 = *(const u16x4*)(Hin + (size_t)c6 * 256 + 4 * lane);
    u16x4 v7 = *(const u16x4*)(Hin + (size_t)c7 * 256 + 4 * lane);
    acc.x = fmaf(w0, bf2f(v0[0]), acc.x); acc.y = fmaf(w0, bf2f(v0[1]), acc.y);
    acc.z = fmaf(w0, bf2f(v0[2]), acc.z); acc.w = fmaf(w0, bf2f(v0[3]), acc.w);
    acc.x = fmaf(w1, bf2f(v1[0]), acc.x); acc.y = fmaf(w1, bf2f(v1[1]), acc.y);
    acc.z = fmaf(w1, bf2f(v1[2]), acc.z); acc.w = fmaf(w1, bf2f(v1[3]), acc.w);
    acc.x = fmaf(w2, bf2f(v2[0]), acc.x); acc.y = fmaf(w2, bf2f(v2[1]), acc.y);
    acc.z = fmaf(w2, bf2f(v2[2]), acc.z); acc.w = fmaf(w2, bf2f(v2[3]), acc.w);
    acc.x = fmaf(w3, bf2f(v3[0]), acc.x); acc.y = fmaf(w3, bf2f(v3[1]), acc.y);
    acc.z = fmaf(w3, bf2f(v3[2]), acc.z); acc.w = fmaf(w3, bf2f(v3[3]), acc.w);
    acc.x = fmaf(w4, bf2f(v4[0]), acc.x); acc.y = fmaf(w4, bf2f(v4[1]), acc.y);
    acc.z = fmaf(w4, bf2f(v4[2]), acc.z); acc.w = fmaf(w4, bf2f(v4[3]), acc.w);
    acc.x = fmaf(w5, bf2f(v5[0]), acc.x); acc.y = fmaf(w5, bf2f(v5[1]), acc.y);
    acc.z = fmaf(w5, bf2f(v5[2]), acc.z); acc.w = fmaf(w5, bf2f(v5[3]), acc.w);
    acc.x = fmaf(w6, bf2f(v6[0]), acc.x); acc.y = fmaf(w6, bf2f(v6[1]), acc.y);
    acc.z = fmaf(w6, bf2f(v6[2]), acc.z); acc.w = fmaf(w6, bf2f(v6[3]), acc.w);
    acc.x = fmaf(w7, bf2f(v7[0]), acc.x); acc.y = fmaf(w7, bf2f(v7[1]), acc.y);
    acc.z = fmaf(w7, bf2f(v7[2]), acc.z); acc.w = fmaf(w7, bf2f(v7[3]), acc.w);
  }
  for (; k < n; ++k) {
    float wv = svw[k];
    u16x4 v = *(const u16x4*)(Hin + (size_t)scw[k] * 256 + 4 * lane);
    acc.x = fmaf(wv, bf2f(v[0]), acc.x); acc.y = fmaf(wv, bf2f(v[1]), acc.y);
    acc.z = fmaf(wv, bf2f(v[2]), acc.z); acc.w = fmaf(wv, bf2f(v[3]), acc.w);
  }
  return acc;
}

// phase-1 helper: gather + bias + leaky + split into LDS for one row r of the tile
__device__ __forceinline__ void spmm_row_to_lds(const u16* __restrict__ Hin,
    const int* scw, const float* svw, int n, int lane, float4 bv,
    u16* AhF, u16* AlF, int r) {
  float4 acc = gather_row256(Hin, scw, svw, n, lane);
  float r4[4] = { leaky_f(acc.x + bv.x), leaky_f(acc.y + bv.y),
                  leaky_f(acc.z + bv.z), leaky_f(acc.w + bv.w) };
  u16x4 hi4, lo4;
#pragma unroll
  for (int e = 0; e < 4; ++e) { u16 hh, ll; split_bf16(r4[e], hh, ll); hi4[e] = hh; lo4[e] = ll; }
  int dst = (lane >> 3) * 640 + r * 40 + (lane & 7) * 4;
  *(u16x4*)(&AhF[dst]) = hi4;
  *(u16x4*)(&AlF[dst]) = lo4;
}

// ---------------- fuse1: x1 = leaky(adj@H0 + b1); T2 = x1 @ W2 (bf16 out, N=256) ----------------
__global__ __launch_bounds__(512) void k_fuse1(const u16* __restrict__ Hin,
    const float* __restrict__ bias, const int* __restrict__ cnt,
    const int* __restrict__ cols, const float* __restrict__ vals,
    const u16* __restrict__ Bt, u16* __restrict__ Cout) {
  __shared__ alignas(16) u16 AhF[8 * 16 * 40], AlF[8 * 16 * 40];  // K-chunked split A (16 rows)
  __shared__ int   sc[16 * CAP];
  __shared__ float sv[16 * CAP];
  int tid = threadIdx.x;
  int wave = tid >> 6, lane = tid & 63, l15 = lane & 15, quad = lane >> 4;
  int bm = blockIdx.x * 16;
  // -------- phase 1: spmm, 2 rows/wave; preload both rows' CSR first --------
  int r0 = wave * 2, r1 = r0 + 1;
  int i0 = bm + r0, i1 = bm + r1;
  int n0 = cnt[i0], n1 = cnt[i1];
  int* sc0 = sc + r0 * CAP;  float* sv0 = sv + r0 * CAP;
  int* sc1 = sc + r1 * CAP;  float* sv1 = sv + r1 * CAP;
  if (lane < n0)      { sc0[lane]      = cols[i0*CAP+lane];    sv0[lane]      = vals[i0*CAP+lane]; }
  if (lane + 64 < n0) { sc0[lane + 64] = cols[i0*CAP+lane+64]; sv0[lane + 64] = vals[i0*CAP+lane+64]; }
  if (lane < n1)      { sc1[lane]      = cols[i1*CAP+lane];    sv1[lane]      = vals[i1*CAP+lane]; }
  if (lane + 64 < n1) { sc1[lane + 64] = cols[i1*CAP+lane+64]; sv1[lane + 64] = vals[i1*CAP+lane+64]; }
  float4 bv = ((const float4*)bias)[lane];
  spmm_row_to_lds(Hin, sc0, sv0, n0, lane, bv, AhF, AlF, r0);
  spmm_row_to_lds(Hin, sc1, sv1, n1, lane, bv, AhF, AlF, r1);
  __syncthreads();
  // -------- phase 2: 16x256 GEMM, 8 waves x 32 cols; B direct from global, no barriers --------
  f32x4 acc[2] = {};
#pragma unroll
  for (int k0 = 0; k0 < D_HID; k0 += 32) {
    bf16x8 afh = *(const bf16x8*)(&AhF[(k0 >> 5) * 640 + l15 * 40 + quad * 8]);
    bf16x8 afl = *(const bf16x8*)(&AlF[(k0 >> 5) * 640 + l15 * 40 + quad * 8]);
#pragma unroll
    for (int c = 0; c < 2; ++c) {
      int col = wave * 32 + c * 16 + l15;
      const u16* bp = Bt + (size_t)col * (2 * D_HID) + k0 + quad * 8;
      bf16x8 bfh = *(const bf16x8*)(bp);
      bf16x8 bfl = *(const bf16x8*)(bp + D_HID);
      acc[c] = __builtin_amdgcn_mfma_f32_16x16x32_bf16(afh, bfh, acc[c], 0, 0, 0);
      acc[c] = __builtin_amdgcn_mfma_f32_16x16x32_bf16(afh, bfl, acc[c], 0, 0, 0);
      acc[c] = __builtin_amdgcn_mfma_f32_16x16x32_bf16(afl, bfh, acc[c], 0, 0, 0);
    }
  }
#pragma unroll
  for (int c = 0; c < 2; ++c)
#pragma unroll
    for (int rg = 0; rg < 4; ++rg) {
      int rowi = bm + quad * 4 + rg;
      int coli = wave * 32 + c * 16 + l15;
      Cout[(size_t)rowi * 256 + coli] = f2bf_rne(acc[c][rg]);
    }
}

// ---------------- fuse2: x2 = leaky(adj@T2 + b2); h = x2 @ Wg (bf16) + fused s1/s2 ----------------
__global__ __launch_bounds__(512) void k_fuse2(const u16* __restrict__ Hin,
    const float* __restrict__ bias, const int* __restrict__ cnt,
    const int* __restrict__ cols, const float* __restrict__ vals,
    const u16* __restrict__ Bt, u16* __restrict__ Hb,
    const float* __restrict__ aptr, float* __restrict__ s1, float* __restrict__ s2) {
  __shared__ alignas(16) u16 AhF[8 * 16 * 40], AlF[8 * 16 * 40];
  __shared__ int   sc[16 * CAP];
  __shared__ float sv[16 * CAP];
  __shared__ float sp1[8][16], sp2[8][16];
  int tid = threadIdx.x;
  int wave = tid >> 6, lane = tid & 63, l15 = lane & 15, quad = lane >> 4;
  int bm = blockIdx.x * 16;
  // -------- phase 1: spmm, 2 rows/wave; preload both rows' CSR first --------
  int r0 = wave * 2, r1 = r0 + 1;
  int i0 = bm + r0, i1 = bm + r1;
  int n0 = cnt[i0], n1 = cnt[i1];
  int* sc0 = sc + r0 * CAP;  float* sv0 = sv + r0 * CAP;
  int* sc1 = sc + r1 * CAP;  float* sv1 = sv + r1 * CAP;
  if (lane < n0)      { sc0[lane]      = cols[i0*CAP+lane];    sv0[lane]      = vals[i0*CAP+lane]; }
  if (lane + 64 < n0) { sc0[lane + 64] = cols[i0*CAP+lane+64]; sv0[lane + 64] = vals[i0*CAP+lane+64]; }
  if (lane < n1)      { sc1[lane]      = cols[i1*CAP+lane];    sv1[lane]      = vals[i1*CAP+lane]; }
  if (lane + 64 < n1) { sc1[lane + 64] = cols[i1*CAP+lane+64]; sv1[lane + 64] = vals[i1*CAP+lane+64]; }
  float4 bv = ((const float4*)bias)[lane];
  spmm_row_to_lds(Hin, sc0, sv0, n0, lane, bv, AhF, AlF, r0);
  spmm_row_to_lds(Hin, sc1, sv1, n1, lane, bv, AhF, AlF, r1);
  __syncthreads();
  // -------- phase 2: 16x128 GEMM, 8 waves x 16 cols; B direct from global; fp32 accs feed s1/s2 --------
  f32x4 acc = {};
#pragma unroll
  for (int k0 = 0; k0 < D_HID; k0 += 32) {
    bf16x8 afh = *(const bf16x8*)(&AhF[(k0 >> 5) * 640 + l15 * 40 + quad * 8]);
    bf16x8 afl = *(const bf16x8*)(&AlF[(k0 >> 5) * 640 + l15 * 40 + quad * 8]);
    int col = wave * 16 + l15;
    const u16* bp = Bt + (size_t)col * (2 * D_HID) + k0 + quad * 8;
    bf16x8 bfh = *(const bf16x8*)(bp);
    bf16x8 bfl = *(const bf16x8*)(bp + D_HID);
    acc = __builtin_amdgcn_mfma_f32_16x16x32_bf16(afh, bfh, acc, 0, 0, 0);
    acc = __builtin_amdgcn_mfma_f32_16x16x32_bf16(afh, bfl, acc, 0, 0, 0);
    acc = __builtin_amdgcn_mfma_f32_16x16x32_bf16(afl, bfh, acc, 0, 0, 0);
  }
  // h write (bf16)
#pragma unroll
  for (int rg = 0; rg < 4; ++rg) {
    int rowi = bm + quad * 4 + rg;
    int coli = wave * 16 + l15;
    Hb[(size_t)rowi * 128 + coli] = f2bf_rne(acc[rg]);
  }
  // fused s1/s2 from fp32 accumulators (exact logit path)
  float a1v = aptr[wave * 16 + l15];
  float a2v = aptr[128 + wave * 16 + l15];
#pragma unroll
  for (int rg = 0; rg < 4; ++rg) {
    float p1 = acc[rg] * a1v;
    float p2 = acc[rg] * a2v;
#pragma unroll
    for (int m = 1; m < 16; m <<= 1) { p1 += __shfl_xor(p1, m); p2 += __shfl_xor(p2, m); }
    if (l15 == 0) {
      int rloc = quad * 4 + rg;
      sp1[wave][rloc] = p1; sp2[wave][rloc] = p2;
    }
  }
  __syncthreads();
  if (tid < 16) {
    float t1 = 0.f, t2 = 0.f;
#pragma unroll
    for (int wv = 0; wv < 8; ++wv) { t1 += sp1[wv][tid]; t2 += sp2[wv][tid]; }
    s1[bm + tid] = t1;
    s2[bm + tid] = t2;
  }
}

// ---------------- attention: ONE WAVE PER ROW; shuffle softmax; 2-half x 4-deep gather MLP ----------------
__global__ __launch_bounds__(256) void k_attn(const u16* __restrict__ Hb,
    const float* __restrict__ s1, const float* __restrict__ s2,
    const int* __restrict__ cnt, const int* __restrict__ cols, float* __restrict__ out) {
  __shared__ int sc[4][CAP];
  __shared__ float sp[4][CAP];
  int w = threadIdx.x >> 6, lane = threadIdx.x & 63;
  int i = blockIdx.x * 4 + w;
  int n = cnt[i];
  float s1i = s1[i];
  float e0 = -1e30f, e1 = -1e30f;
  if (lane < n)      { int c = cols[i * CAP + lane];      sc[w][lane]      = c; e0 = leaky_f(s1i + s2[c]); }
  if (lane + 64 < n) { int c = cols[i * CAP + lane + 64]; sc[w][lane + 64] = c; e1 = leaky_f(s1i + s2[c]); }
  float m = fmaxf(e0, e1);
#pragma unroll
  for (int o = 32; o > 0; o >>= 1) m = fmaxf(m, __shfl_xor(m, o));
  float p0 = (lane < n)      ? expf(e0 - m) : 0.f;
  float p1 = (lane + 64 < n) ? expf(e1 - m) : 0.f;
  if (lane < n)      sp[w][lane]      = p0;
  if (lane + 64 < n) sp[w][lane + 64] = p1;
  float s = p0 + p1;
#pragma unroll
  for (int o = 32; o > 0; o >>= 1) s += __shfl_xor(s, o);
  float inv = (n > 0) ? 1.0f / s : 0.f;
  __syncthreads();
  int half = lane >> 5, t32 = lane & 31;
  float4 acc = {0.f, 0.f, 0.f, 0.f};
  int k = half;
  for (; k + 6 < n; k += 8) {   // per half-wave: 4 independent row-gathers in flight
    int   c0 = sc[w][k],     c1 = sc[w][k + 2], c2 = sc[w][k + 4], c3 = sc[w][k + 6];
    float w0 = sp[w][k],     w1 = sp[w][k + 2], w2 = sp[w][k + 4], w3 = sp[w][k + 6];
    u16x4 a0 = *(const u16x4*)(Hb + (size_t)c0 * 128 + 4 * t32);
    u16x4 a1 = *(const u16x4*)(Hb + (size_t)c1 * 128 + 4 * t32);
    u16x4 a2 = *(const u16x4*)(Hb + (size_t)c2 * 128 + 4 * t32);
    u16x4 a3 = *(const u16x4*)(Hb + (size_t)c3 * 128 + 4 * t32);
    acc.x = fmaf(w0, bf2f(a0[0]), acc.x); acc.y = fmaf(w0, bf2f(a0[1]), acc.y);
    acc.z = fmaf(w0, bf2f(a0[2]), acc.z); acc.w = fmaf(w0, bf2f(a0[3]), acc.w);
    acc.x = fmaf(w1, bf2f(a1[0]), acc.x); acc.y = fmaf(w1, bf2f(a1[1]), acc.y);
    acc.z = fmaf(w1, bf2f(a1[2]), acc.z); acc.w = fmaf(w1, bf2f(a1[3]), acc.w);
    acc.x = fmaf(w2, bf2f(a2[0]), acc.x); acc.y = fmaf(w2, bf2f(a2[1]), acc.y);
    acc.z = fmaf(w2, bf2f(a2[2]), acc.z); acc.w = fmaf(w2, bf2f(a2[3]), acc.w);
    acc.x = fmaf(w3, bf2f(a3[0]), acc.x); acc.y = fmaf(w3, bf2f(a3[1]), acc.y);
    acc.z = fmaf(w3, bf2f(a3[2]), acc.z); acc.w = fmaf(w3, bf2f(a3[3]), acc.w);
  }
  for (; k < n; k += 2) {
    float wv = sp[w][k];
    u16x4 a = *(const u16x4*)(Hb + (size_t)sc[w][k] * 128 + 4 * t32);
    acc.x = fmaf(wv, bf2f(a[0]), acc.x); acc.y = fmaf(wv, bf2f(a[1]), acc.y);
    acc.z = fmaf(wv, bf2f(a[2]), acc.z); acc.w = fmaf(wv, bf2f(a[3]), acc.w);
  }
  acc.x += __shfl_xor(acc.x, 32);
  acc.y += __shfl_xor(acc.y, 32);
  acc.z += __shfl_xor(acc.z, 32);
  acc.w += __shfl_xor(acc.w, 32);
  if (lane < 32) {
    float4 r;
    r.x = leaky_f(acc.x * inv);
    r.y = leaky_f(acc.y * inv);
    r.z = leaky_f(acc.z * inv);
    r.w = leaky_f(acc.w * inv);
    float4* o4 = (float4*)out;
    if (lane < 16) o4[(size_t)i * 16 + lane] = r;                               // mu
    else           o4[(size_t)NROW * 16 + (size_t)i * 16 + (lane - 16)] = r;    // logvar
  }
}

extern "C" void kernel_launch(void* const* d_in, const int* in_sizes, int n_in,
                              void* d_out, int out_size, void* d_ws, size_t ws_size,
                              hipStream_t stream) {
  const float* x   = (const float*)d_in[0];
  const float* adj = (const float*)d_in[1];
  const float* W1  = (const float*)d_in[2];
  const float* b1  = (const float*)d_in[3];
  const float* W2  = (const float*)d_in[4];
  const float* b2  = (const float*)d_in[5];
  const float* Wg  = (const float*)d_in[6];
  const float* a   = (const float*)d_in[7];
  float* out = (float*)d_out;

  char* ws = (char*)d_ws;
  int*   row_cnt  = (int*)  (ws + 0);          //  32 KB
  int*   row_cols = (int*)  (ws + 32768);      //   4 MB
  float* row_vals = (float*)(ws + 4227072);    //   4 MB
  u16*   B1t      = (u16*)  (ws + 8421376);    // 512 KB (256 x 1024)
  u16*   B2t      = (u16*)  (ws + 8945664);    // 256 KB (256 x 512)
  u16*   B3t      = (u16*)  (ws + 9207808);    // 128 KB (128 x 512)
  float* s1       = (float*)(ws + 9338880);    //  32 KB
  float* s2       = (float*)(ws + 9371648);    //  32 KB
  u16*   hbf      = (u16*)  (ws + 9404416);    //   2 MB (8192 x 128 bf16)
  u16*   H0T2     = (u16*)  (ws + 13598720);   //   4 MB (8192 x 256 bf16)
  u16*   T2       = (u16*)  (ws + 21987328);   //   4 MB (8192 x 256 bf16)

  // 1. weight pack (coalesced-store mapping; must precede gemm1)
  k_packw<<<112, 256, 0, stream>>>(W1, B1t, W2, B2t, Wg, B3t);
  // 2. merged: GEMM1 (512 compute blocks, bf16 out) + ballot-scan CSR build (8192 HBM blocks)
  k_csr_gemm1<<<512 + NROW, 256, 0, stream>>>(adj, row_cnt, row_cols, row_vals, x, B1t, H0T2);
  // 3. fused: x1 = leaky(adj@H0 + b1); T2 = x1 @ W2   (8 waves, 2 rows/wave)
  k_fuse1<<<NROW / 16, 512, 0, stream>>>(H0T2, b1, row_cnt, row_cols, row_vals, B2t, T2);
  // 4. fused: x2 = leaky(adj@T2 + b2); h = x2 @ Wg + fused fp32 s1/s2   (8 waves, 2 rows/wave)
  k_fuse2<<<NROW / 16, 512, 0, stream>>>(T2, b2, row_cnt, row_cols, row_vals, B3t, hbf, a, s1, s2);
  // 5. masked softmax attention (wave-per-row, shuffle softmax) + bf16 aggregate + output split
  k_attn<<<NROW / 4, 256, 0, stream>>>(hbf, s1, s2, row_cnt, row_cols, out);
}